// Round 6
// baseline (9534.781 us; speedup 1.0000x reference)
//
#include <hip/hip_runtime.h>

#define TT 512
#define BB 64
#define II 128
#define HH 1024
#define OO 128
#define NWG 196

typedef _Float16 half8 __attribute__((ext_vector_type(8)));
typedef float floatx4 __attribute__((ext_vector_type(4)));

__device__ __forceinline__ float sigm(float x){ return 1.0f/(1.0f + __expf(-x)); }

// ---- L2-cacheable, L1-bypass 16B loads (sc0): XCD L2 dedups the broadcast.
// Batch-issued, NO internal wait. Caller drains vmcnt(0)+sched_barrier.
template<int C, int N, int STRIDE>
struct LdSC {
  static __device__ __forceinline__ void go(half8* d, const _Float16* b){
    asm volatile("global_load_dwordx4 %0, %1, off offset:%2 sc0"
                 : "=v"(d[C]) : "v"(b), "n"(C*STRIDE));
    LdSC<C+1, N, STRIDE>::go(d, b);
  }
};
template<int N, int STRIDE>
struct LdSC<N, N, STRIDE> {
  static __device__ __forceinline__ void go(half8*, const _Float16*){}
};

// write-through-to-LLC stores (bypass L1/L2 -> no dirty lines anywhere)
__device__ __forceinline__ void st_sc(_Float16* p, _Float16 v){
  asm volatile("global_store_short %0, %1, off sc0 sc1" :: "v"(p), "v"(v) : "memory");
}
__device__ __forceinline__ void st_f32(float* p, float v){
  asm volatile("global_store_dword %0, %1, off sc0 sc1" :: "v"(p), "v"(v) : "memory");
}

#define VDRAIN do { asm volatile("s_waitcnt vmcnt(0)" ::: "memory"); \
                    __builtin_amdgcn_sched_barrier(0); } while(0)

// acquire-agent fence: s_waitcnt + buffer_inv (invalidate L1/L2 tags).
// Placed AFTER flag-wait, BEFORE activation loads: stale slot lines (cached
// by epoch t-3 readers, all provably finished before the producer's LLC
// write) are dropped; fills after the fence are fresh from the LLC.
__device__ __forceinline__ void acq_fence(){
  __builtin_amdgcn_fence(__ATOMIC_ACQUIRE, "agent");
  __builtin_amdgcn_sched_barrier(0);
}

// ---- per-wave epoch flag wait (flags live at LLC via agent-scope atomics)
__device__ __forceinline__ void wait_flags(unsigned int* F1, unsigned int* F2,
                                           unsigned int* FP,
                                           int a, int b, int c, int lane){
  for (;;){
    bool ok = true;
    if (a > 0){
#pragma unroll
      for (int k = 0; k < 4; ++k)
        ok &= (int)__hip_atomic_load(&F1[lane + k*64], __ATOMIC_RELAXED,
                                     __HIP_MEMORY_SCOPE_AGENT) >= a;
    }
    if (b > 0){
#pragma unroll
      for (int k = 0; k < 8; ++k)
        ok &= (int)__hip_atomic_load(&F2[lane + k*64], __ATOMIC_RELAXED,
                                     __HIP_MEMORY_SCOPE_AGENT) >= b;
    }
    if (c > 0){
      ok &= (int)__hip_atomic_load(&FP[lane & 15], __ATOMIC_RELAXED,
                                   __HIP_MEMORY_SCOPE_AGENT) >= c;
    }
    if (__all(ok)) break;
    __builtin_amdgcn_s_sleep(1);
  }
}

// ---------------- prep kernels ----------------
__global__ void prep_x_kernel(const float* __restrict__ x, _Float16* __restrict__ X16,
                              unsigned int* __restrict__ bar){
  int idx = blockIdx.x*256 + threadIdx.x;         // idx over [t][b][i]
  if (idx < 1024) bar[idx] = 0u;                  // zero all flag slots
  int i = idx & (II-1);
  int b = (idx >> 7) & (BB-1);
  int t = idx >> 13;
  X16[idx] = (_Float16)x[((size_t)b*TT + t)*II + i];
}

__global__ void prep_w_kernel(const float* __restrict__ wih1, const float* __restrict__ whh1,
                              const float* __restrict__ wih2, const float* __restrict__ whh2,
                              const float* __restrict__ wlin,
                              _Float16* __restrict__ W1, _Float16* __restrict__ W2,
                              _Float16* __restrict__ WL, _Float16* __restrict__ H1,
                              _Float16* __restrict__ H2){
  long idx = (long)blockIdx.x*256 + threadIdx.x;
  const long n1 = 4096L*1152, n2 = 4096L*2048, nl = 128L*1024;
  if (idx < n1){
    int k = (int)(idx % 1152); int j = (int)(idx / 1152);
    W1[idx] = (_Float16)(k < II ? wih1[(size_t)j*II + k] : whh1[(size_t)j*HH + (k-II)]);
  } else if ((idx -= n1) < n2){
    int k = (int)(idx % 2048); int j = (int)(idx / 2048);
    W2[idx] = (_Float16)(k < HH ? wih2[(size_t)j*HH + k] : whh2[(size_t)j*HH + (k-HH)]);
  } else if ((idx -= n2) < nl){
    WL[idx] = (_Float16)wlin[idx];
  } else {
    idx -= nl;                                    // [0, 3*BB*HH): zero 3 slots
    H1[idx] = (_Float16)0.0f;
    H2[idx] = (_Float16)0.0f;
  }
}

// ---------------- persistent dataflow kernel ----------------
// 196 WGs x 512 threads (8 waves = 4 mrow-groups x 2 K-halves).
//   wg   0..63 : layer-1, 16 cols x 4 gates, K=1152 split {x+h[0:512] | h[512:1024]}
//   wg  64..191: layer-2,  8 cols x 4 gates, K=2048 split {h1(t) | h2(t-1)}
//   wg 192..195: projection, 32 cols, K=1024 split {[0:512] | [512:1024]}
// Producers write h via sc0|sc1 (LLC write-through); consumers read via sc0
// (L2-cached, L1-bypass) after a per-wave acquire fence -> the XCD L2 serves
// the broadcast at ~60B/cy instead of each CU pulling 256KB from the LLC.
__global__ void __launch_bounds__(512, 2)
lstm_persist(const _Float16* __restrict__ X16,
             const _Float16* __restrict__ W1,
             const _Float16* __restrict__ W2,
             const _Float16* __restrict__ WL,
             _Float16* __restrict__ H1,
             _Float16* __restrict__ H2,
             const float* __restrict__ bi1, const float* __restrict__ bh1,
             const float* __restrict__ bi2, const float* __restrict__ bh2,
             const float* __restrict__ blin,
             float* __restrict__ out,
             unsigned int* __restrict__ bar)
{
  __shared__ _Float16 WS[73728];        // 147456 B weight slice (XOR-swizzled)
  __shared__ floatx4 RBv[512];          // 8192 B K-half reduction buffer
  char* WSc = (char*)WS;
  unsigned int* F1 = bar;               // [256] layer-1 per-wave flags
  unsigned int* F2 = bar + 256;         // [512] layer-2 per-wave flags
  unsigned int* FP = bar + 768;         // [16]  projection per-wave flags
  const int wg   = blockIdx.x;
  const int tid  = threadIdx.x;
  const int wv   = tid >> 6;            // 0..7
  const int mg   = wv & 3;              // mrow group
  const int kh   = wv >> 2;             // K-half
  const int lane = tid & 63;
  const int q    = lane >> 4;
  const int n    = lane & 15;
  const int mrow = mg << 4;
  const int xr   = (n & 7) << 4;        // LDS XOR-swizzle key
  const int ri   = (mg*64 + lane)*2;    // reduction slot
  const floatx4 zero4 = {0.f, 0.f, 0.f, 0.f};

  if (wg < 64){
    // ================= layer 1 =================
    const int j0 = wg << 4;
    for (int idx = tid; idx < 9216; idx += 512){
      int row = idx / 144, kc = idx - row*144;
      const _Float16* src = W1 + ((size_t)((row>>4)*HH + j0 + (row&15)))*1152 + kc*8;
      *(half8*)(WSc + row*2304 + ((kc*16) ^ ((row&7)<<4))) = *(const half8*)src;
    }
    __syncthreads();

    const int j = j0 + n;
    float bias[4];
    int wrowb[4];
#pragma unroll
    for (int g = 0; g < 4; ++g){
      bias[g]  = bi1[g*HH + j] + bh1[g*HH + j];
      wrowb[g] = (g*16 + n)*2304;
    }
    float c1r[4] = {0.f, 0.f, 0.f, 0.f};
    int cur = 0, prv = 2;
#pragma unroll 1
    for (int t = 0; t < TT; ++t){
      floatx4 acc[4];
#pragma unroll
      for (int g = 0; g < 4; ++g) acc[g] = zero4;
      if (kh == 0){
        // x-part overlaps the flag wait
        const _Float16* xb = X16 + ((size_t)t*BB + (mrow+n))*II + q*8;
        half8 xf[4];
#pragma unroll
        for (int c = 0; c < 4; ++c) xf[c] = *(const half8*)(xb + c*32);
#pragma unroll
        for (int c = 0; c < 4; ++c)
#pragma unroll
          for (int g = 0; g < 4; ++g){
            half8 w = *(const half8*)(WSc + wrowb[g] + ((q*16 + c*64) ^ xr));
            acc[g] = __builtin_amdgcn_mfma_f32_16x16x32_f16(xf[c], w, acc[g], 0, 0, 0);
          }
        wait_flags(F1, F2, FP, t, t-2, 0, lane);   // h1(t-1) ready; slot safe
        acq_fence();
        const _Float16* hb = H1 + ((size_t)prv*BB + (mrow+n))*HH + q*8;
        half8 hA[16];
        LdSC<0,16,64>::go(hA, hb);
        VDRAIN;
#pragma unroll
        for (int g = 0; g < 4; ++g)
#pragma unroll
          for (int c = 0; c < 16; ++c){
            half8 w = *(const half8*)(WSc + wrowb[g] + ((q*16 + (4+c)*64) ^ xr));
            acc[g] = __builtin_amdgcn_mfma_f32_16x16x32_f16(hA[c], w, acc[g], 0, 0, 0);
          }
      } else {
        wait_flags(F1, F2, FP, t, 0, 0, lane);
        acq_fence();
        const _Float16* hb = H1 + ((size_t)prv*BB + (mrow+n))*HH + 512 + q*8;
        half8 hA[16];
        LdSC<0,16,64>::go(hA, hb);
        VDRAIN;
#pragma unroll
        for (int g = 0; g < 4; ++g)
#pragma unroll
          for (int c = 0; c < 16; ++c){
            half8 w = *(const half8*)(WSc + wrowb[g] + ((q*16 + (20+c)*64) ^ xr));
            acc[g] = __builtin_amdgcn_mfma_f32_16x16x32_f16(hA[c], w, acc[g], 0, 0, 0);
          }
      }
      // 2-phase K-half reduction (kh=1 -> kh=0)
      if (kh){ RBv[ri] = acc[0]; RBv[ri+1] = acc[1]; }
      __syncthreads();
      if (!kh){ acc[0] += RBv[ri]; acc[1] += RBv[ri+1]; }
      __syncthreads();
      if (kh){ RBv[ri] = acc[2]; RBv[ri+1] = acc[3]; }
      __syncthreads();
      if (!kh){
        acc[2] += RBv[ri]; acc[3] += RBv[ri+1];
        _Float16* ho = H1 + (size_t)cur*BB*HH;
#pragma unroll
        for (int r = 0; r < 4; ++r){
          const int b = mrow + q*4 + r;
          float gi = acc[0][r] + bias[0];
          float gf = acc[1][r] + bias[1];
          float gg = acc[2][r] + bias[2];
          float go_ = acc[3][r] + bias[3];
          float cc = sigm(gf)*c1r[r] + sigm(gi)*tanhf(gg);
          c1r[r] = cc;
          float h = sigm(go_)*tanhf(cc);
          st_sc(ho + (size_t)b*HH + j, (_Float16)h);
        }
        asm volatile("s_waitcnt vmcnt(0)" ::: "memory");
        if (lane == 0)
          __hip_atomic_store(&F1[wg*4 + mg], (unsigned)(t+1),
                             __ATOMIC_RELAXED, __HIP_MEMORY_SCOPE_AGENT);
      }
      __syncthreads();                   // RB reusable next iteration
      prv = cur; cur = (cur == 2) ? 0 : cur + 1;
    }
  } else if (wg < 192){
    // ================= layer 2 =================
    const int j0 = (wg - 64) << 3;
    for (int idx = tid; idx < 8192; idx += 512){
      int row = idx >> 8, kc = idx & 255;
      const _Float16* src = W2 + ((size_t)((row>>3)*HH + j0 + (row&7)))*2048 + kc*8;
      *(half8*)(WSc + row*4096 + ((kc*16) ^ ((row&7)<<4))) = *(const half8*)src;
    }
    __syncthreads();

    const int jj = j0 + (n & 7);
    float bias[4];
#pragma unroll
    for (int g = 0; g < 4; ++g) bias[g] = bi2[g*HH + jj] + bh2[g*HH + jj];
    const int rbase = (n < 8) ? 0 : 2;
    const int rowb0 = (((n>>3))*8 + (n&7))*4096;       // gates i,f rows
    const int rowb1 = ((2 + (n>>3))*8 + (n&7))*4096;   // gates g,o rows
    float c2r[2] = {0.f, 0.f};
    int cur = 0, prv = 2;
#pragma unroll 1
    for (int t = 0; t < TT; ++t){
      half8 hA[32];
      if (kh == 0){
        wait_flags(F1, F2, FP, t+1, 0, t-2, lane);     // h1(t); slot safe
        acq_fence();
        const _Float16* a = H1 + ((size_t)cur*BB + (mrow+n))*HH + q*8;
        LdSC<0,32,64>::go(hA, a);
      } else {
        wait_flags(F1, F2, FP, 0, t, 0, lane);         // peers' h2(t-1)
        acq_fence();
        const _Float16* a = H2 + ((size_t)prv*BB + (mrow+n))*HH + q*8;
        LdSC<0,32,64>::go(hA, a);
      }
      VDRAIN;
      floatx4 a0 = zero4, a1 = zero4;
      const int cb = kh << 5;
#pragma unroll
      for (int c = 0; c < 32; ++c){
        half8 w0 = *(const half8*)(WSc + rowb0 + ((q*16 + (cb+c)*64) ^ xr));
        a0 = __builtin_amdgcn_mfma_f32_16x16x32_f16(hA[c], w0, a0, 0, 0, 0);
        half8 w1 = *(const half8*)(WSc + rowb1 + ((q*16 + (cb+c)*64) ^ xr));
        a1 = __builtin_amdgcn_mfma_f32_16x16x32_f16(hA[c], w1, a1, 0, 0, 0);
      }
      if (kh){ RBv[ri] = a0; RBv[ri+1] = a1; }
      __syncthreads();
      if (!kh){
        a0 += RBv[ri]; a1 += RBv[ri+1];
        // gather i,f,g,o per (b,jj): lanes n<8 hold (i,g), n>=8 hold (f,o)
        float vi[4], vf[4], vg[4], vo[4];
#pragma unroll
        for (int r = 0; r < 4; ++r){
          float p0 = a0[r], p1 = a1[r];
          float s0 = __shfl_xor(p0, 8, 64);
          float s1 = __shfl_xor(p1, 8, 64);
          vi[r] = (n < 8) ? p0 : s0;
          vf[r] = (n < 8) ? s0 : p0;
          vg[r] = (n < 8) ? p1 : s1;
          vo[r] = (n < 8) ? s1 : p1;
        }
        _Float16* ho = H2 + (size_t)cur*BB*HH;
#pragma unroll
        for (int rr = 0; rr < 2; ++rr){
          int r = rbase + rr;
          const int b = mrow + q*4 + r;
          float gi = vi[r] + bias[0];
          float gf = vf[r] + bias[1];
          float gg = vg[r] + bias[2];
          float go_ = vo[r] + bias[3];
          float cc = sigm(gf)*c2r[rr] + sigm(gi)*tanhf(gg);
          c2r[rr] = cc;
          float h = sigm(go_)*tanhf(cc);
          st_sc(ho + (size_t)b*HH + jj, (_Float16)h);
        }
        asm volatile("s_waitcnt vmcnt(0)" ::: "memory");
        if (lane == 0)
          __hip_atomic_store(&F2[(wg-64)*4 + mg], (unsigned)(t+1),
                             __ATOMIC_RELAXED, __HIP_MEMORY_SCOPE_AGENT);
      }
      __syncthreads();
      prv = cur; cur = (cur == 2) ? 0 : cur + 1;
    }
  } else {
    // ================= output projection =================
    const int j0 = (wg - 192) << 5;
    for (int idx = tid; idx < 4096; idx += 512){
      int row = idx >> 7, kc = idx & 127;
      const _Float16* src = WL + ((size_t)(j0 + row))*1024 + kc*8;
      *(half8*)(WSc + row*2048 + ((kc*16) ^ ((row&7)<<4))) = *(const half8*)src;
    }
    __syncthreads();

    float by[2];
    int rowb[2];
#pragma unroll
    for (int p = 0; p < 2; ++p){
      by[p]   = blin[j0 + p*16 + n];
      rowb[p] = (p*16 + n)*2048;
    }
    int cur = 0;
#pragma unroll 1
    for (int t = 0; t < TT; ++t){
      wait_flags(F1, F2, FP, 0, t+1, 0, lane);         // h2(t) ready
      acq_fence();
      const _Float16* a = H2 + ((size_t)cur*BB + (mrow+n))*HH + kh*512 + q*8;
      half8 hA[16];
      LdSC<0,16,64>::go(hA, a);
      VDRAIN;
      floatx4 a0 = zero4, a1 = zero4;
#pragma unroll
      for (int c = 0; c < 16; ++c){
        half8 w0 = *(const half8*)(WSc + rowb[0] + ((q*16 + (kh*16+c)*64) ^ xr));
        a0 = __builtin_amdgcn_mfma_f32_16x16x32_f16(hA[c], w0, a0, 0, 0, 0);
        half8 w1 = *(const half8*)(WSc + rowb[1] + ((q*16 + (kh*16+c)*64) ^ xr));
        a1 = __builtin_amdgcn_mfma_f32_16x16x32_f16(hA[c], w1, a1, 0, 0, 0);
      }
      if (kh){ RBv[ri] = a0; RBv[ri+1] = a1; }
      __syncthreads();
      if (!kh){
        a0 += RBv[ri]; a1 += RBv[ri+1];
#pragma unroll
        for (int r = 0; r < 4; ++r){
          int b = mrow + q*4 + r;
          st_f32(&out[((size_t)b*TT + t)*OO + (j0 + n)],      a0[r] + by[0]);
          st_f32(&out[((size_t)b*TT + t)*OO + (j0 + 16 + n)], a1[r] + by[1]);
        }
        if (lane == 0)
          __hip_atomic_store(&FP[(wg-192)*4 + mg], (unsigned)(t+1),
                             __ATOMIC_RELAXED, __HIP_MEMORY_SCOPE_AGENT);
      }
      __syncthreads();
      cur = (cur == 2) ? 0 : cur + 1;
    }
  }
}

// ---------------- launch ----------------
extern "C" void kernel_launch(void* const* d_in, const int* in_sizes, int n_in,
                              void* d_out, int out_size, void* d_ws, size_t ws_size,
                              hipStream_t stream){
  const float* x    = (const float*)d_in[0];
  const float* wih1 = (const float*)d_in[1];
  const float* whh1 = (const float*)d_in[2];
  const float* bi1  = (const float*)d_in[3];
  const float* bh1  = (const float*)d_in[4];
  const float* wih2 = (const float*)d_in[5];
  const float* whh2 = (const float*)d_in[6];
  const float* bi2  = (const float*)d_in[7];
  const float* bh2  = (const float*)d_in[8];
  const float* wlin = (const float*)d_in[9];
  const float* blin = (const float*)d_in[10];
  float* out = (float*)d_out;

  char* ws = (char*)d_ws;
  _Float16* X16 = (_Float16*)(ws + 0);          //  8,388,608  [512][64][128]
  _Float16* W1  = (_Float16*)(ws + 8388608);    //  9,437,184  [4096][1152]
  _Float16* W2  = (_Float16*)(ws + 17825792);   // 16,777,216  [4096][2048]
  _Float16* WL  = (_Float16*)(ws + 34603008);   //    262,144  [128][1024]
  _Float16* H1  = (_Float16*)(ws + 34865152);   //    393,216  [3][64][1024]
  _Float16* H2  = (_Float16*)(ws + 35258368);   //    393,216  [3][64][1024]
  unsigned int* bar = (unsigned int*)(ws + 35651584);  // 4096 B flag area
  // total 35,655,680 bytes

  prep_x_kernel<<<dim3(16384), dim3(256), 0, stream>>>(x, X16, bar);
  prep_w_kernel<<<dim3(52480), dim3(256), 0, stream>>>(wih1, whh1, wih2, whh2, wlin,
                                                       W1, W2, WL, H1, H2);
  lstm_persist<<<dim3(NWG), dim3(512), 0, stream>>>(
      X16, W1, W2, WL, H1, H2,
      bi1, bh1, bi2, bh2, blin, out, bar);
}

// Round 7
// 6803.716 us; speedup vs baseline: 1.4014x; 1.4014x over previous
//
#include <hip/hip_runtime.h>

#define TT 512
#define BB 64
#define II 128
#define HH 1024
#define OO 128
#define NWG 196
#define RS 16          // H ring slots (reuse distance 16 steps)

typedef _Float16 half8 __attribute__((ext_vector_type(8)));
typedef float floatx4 __attribute__((ext_vector_type(4)));

__device__ __forceinline__ float sigm(float x){ return 1.0f/(1.0f + __expf(-x)); }

// ---- L2-cacheable, L1-bypass 16B loads (sc0): XCD L2 dedups the broadcast.
// Batch-issued, NO internal wait. Caller drains vmcnt(0)+sched_barrier.
template<int C, int N, int STRIDE>
struct LdSC {
  static __device__ __forceinline__ void go(half8* d, const _Float16* b){
    asm volatile("global_load_dwordx4 %0, %1, off offset:%2 sc0"
                 : "=v"(d[C]) : "v"(b), "n"(C*STRIDE));
    LdSC<C+1, N, STRIDE>::go(d, b);
  }
};
template<int N, int STRIDE>
struct LdSC<N, N, STRIDE> {
  static __device__ __forceinline__ void go(half8*, const _Float16*){}
};

// write-through-to-LLC stores (bypass L1/L2 -> no dirty lines anywhere; an
// L2 invalidate can never lose data)
__device__ __forceinline__ void st_sc(_Float16* p, _Float16 v){
  asm volatile("global_store_short %0, %1, off sc0 sc1" :: "v"(p), "v"(v) : "memory");
}
__device__ __forceinline__ void st_f32(float* p, float v){
  asm volatile("global_store_dword %0, %1, off sc0 sc1" :: "v"(p), "v"(v) : "memory");
}

#define VDRAIN do { asm volatile("s_waitcnt vmcnt(0)" ::: "memory"); \
                    __builtin_amdgcn_sched_barrier(0); } while(0)

// acquire-agent fence (s_waitcnt + buffer_inv). Executed once per WG every
// 8 steps, after the inv-epoch flag wait: all old-generation readers of the
// slots reused in the next 8-step window are flag-proven finished, so no
// stale line can enter L2 after this fence (reads are flag-gated, stores
// are write-through).
__device__ __forceinline__ void acq_fence(){
  __builtin_amdgcn_fence(__ATOMIC_ACQUIRE, "agent");
  __builtin_amdgcn_sched_barrier(0);
}

// ---- per-wave epoch flag wait: all F1>=a, all F2>=b, all FP>=c (skip <=0)
__device__ __forceinline__ void wait_flags(unsigned int* F1, unsigned int* F2,
                                           unsigned int* FP,
                                           int a, int b, int c, int lane){
  for (;;){
    bool ok = true;
    if (a > 0){
#pragma unroll
      for (int k = 0; k < 4; ++k)
        ok &= (int)__hip_atomic_load(&F1[lane + k*64], __ATOMIC_RELAXED,
                                     __HIP_MEMORY_SCOPE_AGENT) >= a;
    }
    if (b > 0){
#pragma unroll
      for (int k = 0; k < 8; ++k)
        ok &= (int)__hip_atomic_load(&F2[lane + k*64], __ATOMIC_RELAXED,
                                     __HIP_MEMORY_SCOPE_AGENT) >= b;
    }
    if (c > 0){
      ok &= (int)__hip_atomic_load(&FP[lane & 15], __ATOMIC_RELAXED,
                                   __HIP_MEMORY_SCOPE_AGENT) >= c;
    }
    if (__all(ok)) break;
    __builtin_amdgcn_s_sleep(1);
  }
}

// ---------------- prep kernels ----------------
__global__ void prep_x_kernel(const float* __restrict__ x, _Float16* __restrict__ X16,
                              unsigned int* __restrict__ bar){
  int idx = blockIdx.x*256 + threadIdx.x;         // idx over [t][b][i]
  if (idx < 1024) bar[idx] = 0u;                  // zero all flag slots
  int i = idx & (II-1);
  int b = (idx >> 7) & (BB-1);
  int t = idx >> 13;
  X16[idx] = (_Float16)x[((size_t)b*TT + t)*II + i];
}

__global__ void prep_w_kernel(const float* __restrict__ wih1, const float* __restrict__ whh1,
                              const float* __restrict__ wih2, const float* __restrict__ whh2,
                              const float* __restrict__ wlin,
                              _Float16* __restrict__ W1, _Float16* __restrict__ W2,
                              _Float16* __restrict__ WL, _Float16* __restrict__ H1,
                              _Float16* __restrict__ H2){
  long idx = (long)blockIdx.x*256 + threadIdx.x;
  const long n1 = 4096L*1152, n2 = 4096L*2048, nl = 128L*1024;
  if (idx < n1){
    int k = (int)(idx % 1152); int j = (int)(idx / 1152);
    W1[idx] = (_Float16)(k < II ? wih1[(size_t)j*II + k] : whh1[(size_t)j*HH + (k-II)]);
  } else if ((idx -= n1) < n2){
    int k = (int)(idx % 2048); int j = (int)(idx / 2048);
    W2[idx] = (_Float16)(k < HH ? wih2[(size_t)j*HH + k] : whh2[(size_t)j*HH + (k-HH)]);
  } else if ((idx -= n2) < nl){
    WL[idx] = (_Float16)wlin[idx];
  } else {
    idx -= nl;                                    // [0, RS*BB*HH): zero all slots
    H1[idx] = (_Float16)0.0f;
    H2[idx] = (_Float16)0.0f;
  }
}

// ---------------- persistent dataflow kernel ----------------
// 196 WGs x 512 threads (8 waves = 4 mrow-groups x 2 K-halves).
//   wg   0..63 : layer-1, 16 cols x 4 gates, K=1152 split {x+h[0:512] | h[512:1024]}
//   wg  64..191: layer-2,  8 cols x 4 gates, K=2048 split {h1(t) | h2(t-1)}
//   wg 192..195: projection, 32 cols, K=1024 split {[0:512] | [512:1024]}
// h lives in 16-slot rings; producers write through to the LLC; consumers
// read via sc0 (L2-cached) -> the XCD L2 serves the intra-XCD broadcast.
// One acquire fence per WG per 8 steps (after the inv-epoch wait) keeps the
// ring slots coherent; stale fills are impossible after the fence because
// all reads are flag-gated and old-generation readers are proven finished.
__global__ void __launch_bounds__(512, 2)
lstm_persist(const _Float16* __restrict__ X16,
             const _Float16* __restrict__ W1,
             const _Float16* __restrict__ W2,
             const _Float16* __restrict__ WL,
             _Float16* __restrict__ H1,
             _Float16* __restrict__ H2,
             const float* __restrict__ bi1, const float* __restrict__ bh1,
             const float* __restrict__ bi2, const float* __restrict__ bh2,
             const float* __restrict__ blin,
             float* __restrict__ out,
             unsigned int* __restrict__ bar)
{
  __shared__ _Float16 WS[73728];        // 147456 B weight slice (XOR-swizzled)
  __shared__ floatx4 RBv[512];          // 8192 B K-half reduction buffer
  char* WSc = (char*)WS;
  unsigned int* F1 = bar;               // [256] layer-1 per-wave flags
  unsigned int* F2 = bar + 256;         // [512] layer-2 per-wave flags
  unsigned int* FP = bar + 768;         // [16]  projection per-wave flags
  const int wg   = blockIdx.x;
  const int tid  = threadIdx.x;
  const int wv   = tid >> 6;            // 0..7
  const int mg   = wv & 3;              // mrow group
  const int kh   = wv >> 2;             // K-half
  const int lane = tid & 63;
  const int q    = lane >> 4;
  const int n    = lane & 15;
  const int mrow = mg << 4;
  const int xr   = (n & 7) << 4;        // LDS XOR-swizzle key
  const int ri   = (mg*64 + lane)*2;    // reduction slot
  const floatx4 zero4 = {0.f, 0.f, 0.f, 0.f};

  if (wg < 64){
    // ================= layer 1 =================
    const int j0 = wg << 4;
    for (int idx = tid; idx < 9216; idx += 512){
      int row = idx / 144, kc = idx - row*144;
      const _Float16* src = W1 + ((size_t)((row>>4)*HH + j0 + (row&15)))*1152 + kc*8;
      *(half8*)(WSc + row*2304 + ((kc*16) ^ ((row&7)<<4))) = *(const half8*)src;
    }
    __syncthreads();

    const int j = j0 + n;
    float bias[4];
    int wrowb[4];
#pragma unroll
    for (int g = 0; g < 4; ++g){
      bias[g]  = bi1[g*HH + j] + bh1[g*HH + j];
      wrowb[g] = (g*16 + n)*2304;
    }
    float c1r[4] = {0.f, 0.f, 0.f, 0.f};
#pragma unroll 1
    for (int t = 0; t < TT; ++t){
      const int cur = t & (RS-1), prv = (t-1) & (RS-1);
      const bool invs = ((t & 7) == 0);
      floatx4 acc[4];
#pragma unroll
      for (int g = 0; g < 4; ++g) acc[g] = zero4;
      if (kh == 0){
        // x-part overlaps the flag wait
        const _Float16* xb = X16 + ((size_t)t*BB + (mrow+n))*II + q*8;
        half8 xf[4];
#pragma unroll
        for (int c = 0; c < 4; ++c) xf[c] = *(const half8*)(xb + c*32);
#pragma unroll
        for (int c = 0; c < 4; ++c)
#pragma unroll
          for (int g = 0; g < 4; ++g){
            half8 w = *(const half8*)(WSc + wrowb[g] + ((q*16 + c*64) ^ xr));
            acc[g] = __builtin_amdgcn_mfma_f32_16x16x32_f16(xf[c], w, acc[g], 0, 0, 0);
          }
        wait_flags(F1, F2, FP, t, invs ? t-1 : 0, invs ? t-2 : 0, lane);
        if (invs) acq_fence();
        const _Float16* hb = H1 + ((size_t)prv*BB + (mrow+n))*HH + q*8;
        half8 hA[16];
        LdSC<0,16,64>::go(hA, hb);
        VDRAIN;
#pragma unroll
        for (int g = 0; g < 4; ++g)
#pragma unroll
          for (int c = 0; c < 16; ++c){
            half8 w = *(const half8*)(WSc + wrowb[g] + ((q*16 + (4+c)*64) ^ xr));
            acc[g] = __builtin_amdgcn_mfma_f32_16x16x32_f16(hA[c], w, acc[g], 0, 0, 0);
          }
      } else {
        wait_flags(F1, F2, FP, t, invs ? t-1 : 0, invs ? t-2 : 0, lane);
        if (invs) acq_fence();
        const _Float16* hb = H1 + ((size_t)prv*BB + (mrow+n))*HH + 512 + q*8;
        half8 hA[16];
        LdSC<0,16,64>::go(hA, hb);
        VDRAIN;
#pragma unroll
        for (int g = 0; g < 4; ++g)
#pragma unroll
          for (int c = 0; c < 16; ++c){
            half8 w = *(const half8*)(WSc + wrowb[g] + ((q*16 + (20+c)*64) ^ xr));
            acc[g] = __builtin_amdgcn_mfma_f32_16x16x32_f16(hA[c], w, acc[g], 0, 0, 0);
          }
      }
      // 2-phase K-half reduction (kh=1 -> kh=0)
      if (kh){ RBv[ri] = acc[0]; RBv[ri+1] = acc[1]; }
      __syncthreads();
      if (!kh){ acc[0] += RBv[ri]; acc[1] += RBv[ri+1]; }
      __syncthreads();
      if (kh){ RBv[ri] = acc[2]; RBv[ri+1] = acc[3]; }
      __syncthreads();
      if (!kh){
        acc[2] += RBv[ri]; acc[3] += RBv[ri+1];
        _Float16* ho = H1 + (size_t)cur*BB*HH;
#pragma unroll
        for (int r = 0; r < 4; ++r){
          const int b = mrow + q*4 + r;
          float gi = acc[0][r] + bias[0];
          float gf = acc[1][r] + bias[1];
          float gg = acc[2][r] + bias[2];
          float go_ = acc[3][r] + bias[3];
          float cc = sigm(gf)*c1r[r] + sigm(gi)*tanhf(gg);
          c1r[r] = cc;
          float h = sigm(go_)*tanhf(cc);
          st_sc(ho + (size_t)b*HH + j, (_Float16)h);
        }
        asm volatile("s_waitcnt vmcnt(0)" ::: "memory");
        if (lane == 0)
          __hip_atomic_store(&F1[wg*4 + mg], (unsigned)(t+1),
                             __ATOMIC_RELAXED, __HIP_MEMORY_SCOPE_AGENT);
      }
      __syncthreads();                   // RB reusable next iteration
    }
  } else if (wg < 192){
    // ================= layer 2 =================
    const int j0 = (wg - 64) << 3;
    for (int idx = tid; idx < 8192; idx += 512){
      int row = idx >> 8, kc = idx & 255;
      const _Float16* src = W2 + ((size_t)((row>>3)*HH + j0 + (row&7)))*2048 + kc*8;
      *(half8*)(WSc + row*4096 + ((kc*16) ^ ((row&7)<<4))) = *(const half8*)src;
    }
    __syncthreads();

    const int jj = j0 + (n & 7);
    float bias[4];
#pragma unroll
    for (int g = 0; g < 4; ++g) bias[g] = bi2[g*HH + jj] + bh2[g*HH + jj];
    const int rbase = (n < 8) ? 0 : 2;
    const int rowb0 = (((n>>3))*8 + (n&7))*4096;       // gates i,f rows
    const int rowb1 = ((2 + (n>>3))*8 + (n&7))*4096;   // gates g,o rows
    float c2r[2] = {0.f, 0.f};
#pragma unroll 1
    for (int t = 0; t < TT; ++t){
      const int cur = t & (RS-1), prv = (t-1) & (RS-1);
      const bool invs = ((t & 7) == 0);
      half8 hA[32];
      if (kh == 0){
        wait_flags(F1, F2, FP, t+1, invs ? t-1 : 0, invs ? t-2 : 0, lane);
        if (invs) acq_fence();
        const _Float16* a = H1 + ((size_t)cur*BB + (mrow+n))*HH + q*8;
        LdSC<0,32,64>::go(hA, a);
      } else {
        wait_flags(F1, F2, FP, invs ? t : 0, t, invs ? t-2 : 0, lane);
        if (invs) acq_fence();
        const _Float16* a = H2 + ((size_t)prv*BB + (mrow+n))*HH + q*8;
        LdSC<0,32,64>::go(hA, a);
      }
      VDRAIN;
      floatx4 a0 = zero4, a1 = zero4;
      const int cb = kh << 5;
#pragma unroll
      for (int c = 0; c < 32; ++c){
        half8 w0 = *(const half8*)(WSc + rowb0 + ((q*16 + (cb+c)*64) ^ xr));
        a0 = __builtin_amdgcn_mfma_f32_16x16x32_f16(hA[c], w0, a0, 0, 0, 0);
        half8 w1 = *(const half8*)(WSc + rowb1 + ((q*16 + (cb+c)*64) ^ xr));
        a1 = __builtin_amdgcn_mfma_f32_16x16x32_f16(hA[c], w1, a1, 0, 0, 0);
      }
      if (kh){ RBv[ri] = a0; RBv[ri+1] = a1; }
      __syncthreads();
      if (!kh){
        a0 += RBv[ri]; a1 += RBv[ri+1];
        // gather i,f,g,o per (b,jj): lanes n<8 hold (i,g), n>=8 hold (f,o)
        float vi[4], vf[4], vg[4], vo[4];
#pragma unroll
        for (int r = 0; r < 4; ++r){
          float p0 = a0[r], p1 = a1[r];
          float s0 = __shfl_xor(p0, 8, 64);
          float s1 = __shfl_xor(p1, 8, 64);
          vi[r] = (n < 8) ? p0 : s0;
          vf[r] = (n < 8) ? s0 : p0;
          vg[r] = (n < 8) ? p1 : s1;
          vo[r] = (n < 8) ? s1 : p1;
        }
        _Float16* ho = H2 + (size_t)cur*BB*HH;
#pragma unroll
        for (int rr = 0; rr < 2; ++rr){
          int r = rbase + rr;
          const int b = mrow + q*4 + r;
          float gi = vi[r] + bias[0];
          float gf = vf[r] + bias[1];
          float gg = vg[r] + bias[2];
          float go_ = vo[r] + bias[3];
          float cc = sigm(gf)*c2r[rr] + sigm(gi)*tanhf(gg);
          c2r[rr] = cc;
          float h = sigm(go_)*tanhf(cc);
          st_sc(ho + (size_t)b*HH + jj, (_Float16)h);
        }
        asm volatile("s_waitcnt vmcnt(0)" ::: "memory");
        if (lane == 0)
          __hip_atomic_store(&F2[(wg-64)*4 + mg], (unsigned)(t+1),
                             __ATOMIC_RELAXED, __HIP_MEMORY_SCOPE_AGENT);
      }
      __syncthreads();
    }
  } else {
    // ================= output projection =================
    const int j0 = (wg - 192) << 5;
    for (int idx = tid; idx < 4096; idx += 512){
      int row = idx >> 7, kc = idx & 127;
      const _Float16* src = WL + ((size_t)(j0 + row))*1024 + kc*8;
      *(half8*)(WSc + row*2048 + ((kc*16) ^ ((row&7)<<4))) = *(const half8*)src;
    }
    __syncthreads();

    float by[2];
    int rowb[2];
#pragma unroll
    for (int p = 0; p < 2; ++p){
      by[p]   = blin[j0 + p*16 + n];
      rowb[p] = (p*16 + n)*2048;
    }
#pragma unroll 1
    for (int t = 0; t < TT; ++t){
      const int cur = t & (RS-1);
      const bool invs = ((t & 7) == 0);
      wait_flags(F1, F2, FP, invs ? t : 0, t+1, invs ? t-2 : 0, lane);
      if (invs) acq_fence();
      const _Float16* a = H2 + ((size_t)cur*BB + (mrow+n))*HH + kh*512 + q*8;
      half8 hA[16];
      LdSC<0,16,64>::go(hA, a);
      VDRAIN;
      floatx4 a0 = zero4, a1 = zero4;
#pragma unroll
      for (int c = 0; c < 16; ++c){
        half8 w0 = *(const half8*)(WSc + rowb[0] + ((q*16 + (kh*16+c)*64) ^ xr));
        a0 = __builtin_amdgcn_mfma_f32_16x16x32_f16(hA[c], w0, a0, 0, 0, 0);
        half8 w1 = *(const half8*)(WSc + rowb[1] + ((q*16 + (kh*16+c)*64) ^ xr));
        a1 = __builtin_amdgcn_mfma_f32_16x16x32_f16(hA[c], w1, a1, 0, 0, 0);
      }
      if (kh){ RBv[ri] = a0; RBv[ri+1] = a1; }
      __syncthreads();
      if (!kh){
        a0 += RBv[ri]; a1 += RBv[ri+1];
#pragma unroll
        for (int r = 0; r < 4; ++r){
          int b = mrow + q*4 + r;
          st_f32(&out[((size_t)b*TT + t)*OO + (j0 + n)],      a0[r] + by[0]);
          st_f32(&out[((size_t)b*TT + t)*OO + (j0 + 16 + n)], a1[r] + by[1]);
        }
        if (lane == 0)
          __hip_atomic_store(&FP[(wg-192)*4 + mg], (unsigned)(t+1),
                             __ATOMIC_RELAXED, __HIP_MEMORY_SCOPE_AGENT);
      }
      __syncthreads();
    }
  }
}

// ---------------- launch ----------------
extern "C" void kernel_launch(void* const* d_in, const int* in_sizes, int n_in,
                              void* d_out, int out_size, void* d_ws, size_t ws_size,
                              hipStream_t stream){
  const float* x    = (const float*)d_in[0];
  const float* wih1 = (const float*)d_in[1];
  const float* whh1 = (const float*)d_in[2];
  const float* bi1  = (const float*)d_in[3];
  const float* bh1  = (const float*)d_in[4];
  const float* wih2 = (const float*)d_in[5];
  const float* whh2 = (const float*)d_in[6];
  const float* bi2  = (const float*)d_in[7];
  const float* bh2  = (const float*)d_in[8];
  const float* wlin = (const float*)d_in[9];
  const float* blin = (const float*)d_in[10];
  float* out = (float*)d_out;

  char* ws = (char*)d_ws;
  _Float16* X16 = (_Float16*)(ws + 0);          //  8,388,608  [512][64][128]
  _Float16* W1  = (_Float16*)(ws + 8388608);    //  9,437,184  [4096][1152]
  _Float16* W2  = (_Float16*)(ws + 17825792);   // 16,777,216  [4096][2048]
  _Float16* WL  = (_Float16*)(ws + 34603008);   //    262,144  [128][1024]
  _Float16* H1  = (_Float16*)(ws + 34865152);   //  2,097,152  [16][64][1024]
  _Float16* H2  = (_Float16*)(ws + 36962304);   //  2,097,152  [16][64][1024]
  unsigned int* bar = (unsigned int*)(ws + 39059456);  // 4096 B flag area
  // total 39,063,552 bytes

  prep_x_kernel<<<dim3(16384), dim3(256), 0, stream>>>(x, X16, bar);
  prep_w_kernel<<<dim3(55808), dim3(256), 0, stream>>>(wih1, whh1, wih2, whh2, wlin,
                                                       W1, W2, WL, H1, H2);
  lstm_persist<<<dim3(NWG), dim3(512), 0, stream>>>(
      X16, W1, W2, WL, H1, H2,
      bi1, bh1, bi2, bh2, blin, out, bar);
}